// Round 1
// baseline (1909.046 us; speedup 1.0000x reference)
//
#include <hip/hip_runtime.h>

#define NB 4
#define NP 8192
#define NS 1024
#define NK 32
#define CNT_ALL 131072.0f   // NB*NS*NK

// ---------------------------------------------------------------- FPS
__global__ __launch_bounds__(256) void fps_kernel(const float* __restrict__ xyz,
                                                  float* __restrict__ newxyz)
{
#pragma clang fp contract(off)
    const int b = blockIdx.x;
    const int tid = threadIdx.x;
    const float* xb = xyz + (size_t)b * NP * 3;
    float px[32], py[32], pz[32], dist[32];
#pragma unroll
    for (int j = 0; j < 32; ++j) {
        const int p = tid + (j << 8);
        px[j] = xb[p * 3 + 0];
        py[j] = xb[p * 3 + 1];
        pz[j] = xb[p * 3 + 2];
        dist[j] = 1e10f;
    }
    __shared__ float s_bd[4];
    __shared__ int   s_bi[4];
    __shared__ float s_c[3];
    if (tid == 0) { s_c[0] = xb[0]; s_c[1] = xb[1]; s_c[2] = xb[2]; }
    __syncthreads();
    float cx = s_c[0], cy = s_c[1], cz = s_c[2];
    float* ob = newxyz + (size_t)b * NS * 3;
    for (int it = 0; it < NS; ++it) {
        if (tid == 0) { ob[it * 3 + 0] = cx; ob[it * 3 + 1] = cy; ob[it * 3 + 2] = cz; }
        float bd = -1.0f; int bi = 0;
#pragma unroll
        for (int j = 0; j < 32; ++j) {
            float dx = px[j] - cx, dy = py[j] - cy, dz = pz[j] - cz;
            float d = (dx * dx + dy * dy) + dz * dz;   // match numpy order, no fma
            float dj = fminf(dist[j], d);
            dist[j] = dj;
            bool t = dj > bd;                           // strict > : first-occurrence tie-break
            bd = t ? dj : bd;
            bi = t ? (tid + (j << 8)) : bi;
        }
#pragma unroll
        for (int m = 1; m < 64; m <<= 1) {
            float od = __shfl_xor(bd, m);
            int   oi = __shfl_xor(bi, m);
            bool t = (od > bd) || (od == bd && oi < bi);
            bd = t ? od : bd;
            bi = t ? oi : bi;
        }
        if ((tid & 63) == 0) { s_bd[tid >> 6] = bd; s_bi[tid >> 6] = bi; }
        __syncthreads();
        if (tid == 0) {
            float fd = s_bd[0]; int fi = s_bi[0];
            for (int u = 1; u < 4; ++u) {
                bool t = (s_bd[u] > fd) || (s_bd[u] == fd && s_bi[u] < fi);
                fd = t ? s_bd[u] : fd;
                fi = t ? s_bi[u] : fi;
            }
            const float* cp = xb + (size_t)fi * 3;
            s_c[0] = cp[0]; s_c[1] = cp[1]; s_c[2] = cp[2];
        }
        __syncthreads();
        cx = s_c[0]; cy = s_c[1]; cz = s_c[2];
    }
}

// ---------------------------------------------------------------- ball query
// one wave per centroid; collect first NK point-indices (ascending) with d^2 <= r^2
__global__ __launch_bounds__(256) void ballq_kernel(const float* __restrict__ xyz,
                                                    const float* __restrict__ newxyz,
                                                    int* __restrict__ idxb)
{
#pragma clang fp contract(off)
    __shared__ int s_ball[4][NK];
    const int w = threadIdx.x >> 6;
    const int lane = threadIdx.x & 63;
    const int sg = blockIdx.x * 4 + w;          // 0..4095
    const int b = sg >> 10;
    const float rr = (float)(0.2 * 0.2);        // == f32(0.04000000000000001)
    const float cx = newxyz[sg * 3 + 0];
    const float cy = newxyz[sg * 3 + 1];
    const float cz = newxyz[sg * 3 + 2];
    const float* xb = xyz + (size_t)b * NP * 3;
    int cnt = 0;
    for (int base = 0; base < NP && cnt < NK; base += 64) {
        const int p = base + lane;
        float dx = xb[p * 3 + 0] - cx;
        float dy = xb[p * 3 + 1] - cy;
        float dz = xb[p * 3 + 2] - cz;
        float d = (dx * dx + dy * dy) + dz * dz;
        bool in = (d <= rr);
        unsigned long long mask = __ballot(in);
        int before = __popcll(mask & ((1ull << lane) - 1ull));
        int pos = cnt + before;
        if (in && pos < NK) s_ball[w][pos] = p;
        cnt += (int)__popcll(mask);
    }
    cnt = min(cnt, NK);
    if (lane < NK) {
        int v = (lane < cnt) ? s_ball[w][lane] : s_ball[w][0];
        idxb[(size_t)sg * NK + lane] = v;
    }
}

// ---------------------------------------------------------------- layer 1 (19 -> 64), pre-BN output
__global__ __launch_bounds__(256) void linear1_kernel(const float* __restrict__ xyz,
                                                      const float* __restrict__ pts,
                                                      const float* __restrict__ newxyz,
                                                      const int* __restrict__ idxb,
                                                      const float* __restrict__ w1,
                                                      const float* __restrict__ b1,
                                                      float* __restrict__ y1)
{
    const int P = blockIdx.x * 256 + threadIdx.x;    // 0..131071
    const int b = P >> 15;
    const int s = (P >> 5) & (NS - 1);
    const int id = idxb[P];
    const float* pp = xyz + ((size_t)b * NP + id) * 3;
    const float* cp = newxyz + ((size_t)b * NS + s) * 3;
    float f[19];
    f[0] = pp[0] - cp[0];
    f[1] = pp[1] - cp[1];
    f[2] = pp[2] - cp[2];
    const float* q = pts + ((size_t)b * NP + id) * 16;
#pragma unroll
    for (int j = 0; j < 16; ++j) f[3 + j] = q[j];
    float y[64];
#pragma unroll 4
    for (int c = 0; c < 64; ++c) {
        float a = b1[c];
#pragma unroll
        for (int j = 0; j < 19; ++j) a += w1[c * 19 + j] * f[j];
        y[c] = a;
    }
    float4* o = (float4*)(y1 + (size_t)P * 64);
#pragma unroll
    for (int t = 0; t < 16; ++t) o[t] = make_float4(y[4*t], y[4*t+1], y[4*t+2], y[4*t+3]);
}

// ---------------------------------------------------------------- per-channel sum/sumsq reduction
template <int C>
__global__ __launch_bounds__(256) void stats_kernel(const float* __restrict__ y,
                                                    float* __restrict__ sums,
                                                    float* __restrict__ sqs)
{
    const int RPB = 256 / C;
    const int c = threadIdx.x & (C - 1);
    const int rq = threadIdx.x / C;
    float s = 0.f, q = 0.f;
    for (int r = blockIdx.x * RPB + rq; r < 131072; r += gridDim.x * RPB) {
        float v = y[(size_t)r * C + c];
        s += v; q += v * v;
    }
    __shared__ float ls[256], lq[256];
    ls[threadIdx.x] = s; lq[threadIdx.x] = q;
    __syncthreads();
    if (threadIdx.x < C) {
        for (int i = 1; i < RPB; ++i) { s += ls[i * C + threadIdx.x]; q += lq[i * C + threadIdx.x]; }
        atomicAdd(&sums[(blockIdx.x & 7) * C + threadIdx.x], s);
        atomicAdd(&sqs [(blockIdx.x & 7) * C + threadIdx.x], q);
    }
}

template <int C>
__global__ void finalize_kernel(const float* __restrict__ sums, const float* __restrict__ sqs,
                                const float* __restrict__ g, const float* __restrict__ be,
                                float* __restrict__ scale, float* __restrict__ shift)
{
    const int c = threadIdx.x;
    if (c >= C) return;
    float s = 0.f, q = 0.f;
    for (int sh = 0; sh < 8; ++sh) { s += sums[sh * C + c]; q += sqs[sh * C + c]; }
    float mean = s / CNT_ALL;
    float var = q / CNT_ALL - mean * mean;
    float sc = g[c] / sqrtf(var + 1e-5f);
    scale[c] = sc;
    shift[c] = be[c] - mean * sc;
}

// ---------------------------------------------------------------- layer 2 (64 -> 64), pre-BN output
__global__ __launch_bounds__(256) void linear2_kernel(const float* __restrict__ y1,
                                                      const float* __restrict__ sc1,
                                                      const float* __restrict__ sh1,
                                                      const float* __restrict__ w2,
                                                      const float* __restrict__ b2,
                                                      float* __restrict__ y2)
{
    const int P = blockIdx.x * 256 + threadIdx.x;
    const float4* yi = (const float4*)(y1 + (size_t)P * 64);
    float x[64];
#pragma unroll
    for (int t = 0; t < 16; ++t) {
        float4 v = yi[t];
        x[4*t+0] = fmaxf(v.x * sc1[4*t+0] + sh1[4*t+0], 0.f);
        x[4*t+1] = fmaxf(v.y * sc1[4*t+1] + sh1[4*t+1], 0.f);
        x[4*t+2] = fmaxf(v.z * sc1[4*t+2] + sh1[4*t+2], 0.f);
        x[4*t+3] = fmaxf(v.w * sc1[4*t+3] + sh1[4*t+3], 0.f);
    }
    float y[64];
#pragma unroll 4
    for (int c = 0; c < 64; ++c) {
        float a = b2[c];
#pragma unroll
        for (int j = 0; j < 64; ++j) a += w2[c * 64 + j] * x[j];
        y[c] = a;
    }
    float4* o = (float4*)(y2 + (size_t)P * 64);
#pragma unroll
    for (int t = 0; t < 16; ++t) o[t] = make_float4(y[4*t], y[4*t+1], y[4*t+2], y[4*t+3]);
}

// ---------------------------------------------------------------- bn2+relu elementwise -> x2
__global__ __launch_bounds__(256) void bnrelu_kernel(const float* __restrict__ y2,
                                                     const float* __restrict__ sc,
                                                     const float* __restrict__ sh,
                                                     float* __restrict__ x2)
{
    const int i = blockIdx.x * 256 + threadIdx.x;    // float4 index, 2097152 total
    float4 v = ((const float4*)y2)[i];
    const int c = (i * 4) & 63;
    float4 o;
    o.x = fmaxf(v.x * sc[c + 0] + sh[c + 0], 0.f);
    o.y = fmaxf(v.y * sc[c + 1] + sh[c + 1], 0.f);
    o.z = fmaxf(v.z * sc[c + 2] + sh[c + 2], 0.f);
    o.w = fmaxf(v.w * sc[c + 3] + sh[c + 3], 0.f);
    ((float4*)x2)[i] = o;
}

// ---------------------------------------------------------------- layer 3 stats (no y3 store)
__global__ __launch_bounds__(128) void l3stats_kernel(const float* __restrict__ x2,
                                                      const float* __restrict__ w3,
                                                      const float* __restrict__ b3,
                                                      float* __restrict__ sums,
                                                      float* __restrict__ sqs)
{
    const int g = blockIdx.x;       // 4096 groups (b*NS+s)
    const int c = threadIdx.x;      // 128 channels
    float w[64];
    const float4* wr = (const float4*)(w3 + (size_t)c * 64);
#pragma unroll
    for (int t = 0; t < 16; ++t) {
        float4 v = wr[t];
        w[4*t+0] = v.x; w[4*t+1] = v.y; w[4*t+2] = v.z; w[4*t+3] = v.w;
    }
    const float bs = b3[c];
    float s = 0.f, q = 0.f;
    const float* xg = x2 + (size_t)g * NK * 64;
#pragma unroll 2
    for (int k = 0; k < NK; ++k) {
        const float4* xk = (const float4*)(xg + k * 64);
        float a = bs;
#pragma unroll
        for (int t = 0; t < 16; ++t) {
            float4 v = xk[t];
            a += w[4*t+0] * v.x + w[4*t+1] * v.y + w[4*t+2] * v.z + w[4*t+3] * v.w;
        }
        s += a; q += a * a;
    }
    atomicAdd(&sums[(g & 7) * 128 + c], s);
    atomicAdd(&sqs [(g & 7) * 128 + c], q);
}

// ---------------------------------------------------------------- layer 3 recompute + bn3 + relu + maxpool
__global__ __launch_bounds__(128) void final_kernel(const float* __restrict__ x2,
                                                    const float* __restrict__ w3,
                                                    const float* __restrict__ b3,
                                                    const float* __restrict__ sc3,
                                                    const float* __restrict__ sh3,
                                                    float* __restrict__ out_np)
{
    const int g = blockIdx.x;
    const int c = threadIdx.x;
    float w[64];
    const float4* wr = (const float4*)(w3 + (size_t)c * 64);
#pragma unroll
    for (int t = 0; t < 16; ++t) {
        float4 v = wr[t];
        w[4*t+0] = v.x; w[4*t+1] = v.y; w[4*t+2] = v.z; w[4*t+3] = v.w;
    }
    const float bs = b3[c];
    const float sc = sc3[c], sh = sh3[c];
    float m = -1e30f;
    const float* xg = x2 + (size_t)g * NK * 64;
#pragma unroll 2
    for (int k = 0; k < NK; ++k) {
        const float4* xk = (const float4*)(xg + k * 64);
        float a = bs;
#pragma unroll
        for (int t = 0; t < 16; ++t) {
            float4 v = xk[t];
            a += w[4*t+0] * v.x + w[4*t+1] * v.y + w[4*t+2] * v.z + w[4*t+3] * v.w;
        }
        float r = fmaxf(a * sc + sh, 0.f);
        m = fmaxf(m, r);
    }
    out_np[(size_t)g * 128 + c] = m;
}

// ---------------------------------------------------------------- host launch
extern "C" void kernel_launch(void* const* d_in, const int* in_sizes, int n_in,
                              void* d_out, int out_size, void* d_ws, size_t ws_size,
                              hipStream_t stream)
{
    (void)in_sizes; (void)n_in; (void)out_size;
    const float* xyz = (const float*)d_in[0];
    const float* pts = (const float*)d_in[1];
    const float* w1 = (const float*)d_in[2];
    const float* b1 = (const float*)d_in[3];
    const float* g1 = (const float*)d_in[4];
    const float* be1 = (const float*)d_in[5];
    const float* w2 = (const float*)d_in[6];
    const float* b2 = (const float*)d_in[7];
    const float* g2 = (const float*)d_in[8];
    const float* be2 = (const float*)d_in[9];
    const float* w3 = (const float*)d_in[10];
    const float* b3 = (const float*)d_in[11];
    const float* g3 = (const float*)d_in[12];
    const float* be3 = (const float*)d_in[13];

    float* out = (float*)d_out;
    float* newxyz = out;              // 4*1024*3
    float* newpts = out + NB * NS * 3;

    char* w = (char*)d_ws;
    int* idxb = (int*)w;                               // 131072 ints = 512 KB
    float* y1 = (float*)(w + (512 << 10));             // 8388608 f32
    float* y2 = y1 + 8388608;
    float* x2 = y2 + 8388608;
    float* st = x2 + 8388608;                          // stats: 3 layers * 2304 f32
    const size_t needed = (512ull << 10) + 3ull * 8388608ull * 4ull + 3ull * 2304ull * 4ull;
    if (ws_size < needed) return;                       // ws too small: bail cleanly

    float* sums1 = st,          *sqs1 = st + 1024,  *sc1 = st + 2048, *sh1 = st + 2176;
    float* st2 = st + 2304;
    float* sums2 = st2,         *sqs2 = st2 + 1024, *sc2 = st2 + 2048, *sh2 = st2 + 2176;
    float* st3 = st + 4608;
    float* sums3 = st3,         *sqs3 = st3 + 1024, *sc3 = st3 + 2048, *sh3 = st3 + 2176;

    hipMemsetAsync(st, 0, 3ull * 2304ull * 4ull, stream);

    fps_kernel<<<NB, 256, 0, stream>>>(xyz, newxyz);
    ballq_kernel<<<1024, 256, 0, stream>>>(xyz, newxyz, idxb);
    linear1_kernel<<<512, 256, 0, stream>>>(xyz, pts, newxyz, idxb, w1, b1, y1);
    stats_kernel<64><<<512, 256, 0, stream>>>(y1, sums1, sqs1);
    finalize_kernel<64><<<1, 64, 0, stream>>>(sums1, sqs1, g1, be1, sc1, sh1);
    linear2_kernel<<<512, 256, 0, stream>>>(y1, sc1, sh1, w2, b2, y2);
    stats_kernel<64><<<512, 256, 0, stream>>>(y2, sums2, sqs2);
    finalize_kernel<64><<<1, 64, 0, stream>>>(sums2, sqs2, g2, be2, sc2, sh2);
    bnrelu_kernel<<<8192, 256, 0, stream>>>(y2, sc2, sh2, x2);
    l3stats_kernel<<<4096, 128, 0, stream>>>(x2, w3, b3, sums3, sqs3);
    finalize_kernel<128><<<1, 128, 0, stream>>>(sums3, sqs3, g3, be3, sc3, sh3);
    final_kernel<<<4096, 128, 0, stream>>>(x2, w3, b3, sc3, sh3, newpts);
}

// Round 2
// 1626.045 us; speedup vs baseline: 1.1740x; 1.1740x over previous
//
#include <hip/hip_runtime.h>

#define NB 4
#define NP 8192
#define NS 1024
#define NK 32
#define CNT_ALL 131072.0f   // NB*NS*NK

// ---------------------------------------------------------------- FPS
// One block per batch. 256 threads, 32 points/thread held entirely in VGPRs
// (launch_bounds(256,1): 4 waves on 4 SIMDs of one CU, VGPR cap 512 -> no spill).
// Per iteration: register distance update + packed-u64 argmax butterfly +
// single barrier cross-wave combine (double-buffered LDS keys).
__global__ __launch_bounds__(256, 1) void fps_kernel(const float* __restrict__ xyz,
                                                     float* __restrict__ newxyz)
{
#pragma clang fp contract(off)
    const int b = blockIdx.x;
    const int tid = threadIdx.x;
    const int lane = tid & 63;
    const int w = tid >> 6;
    const float* xb = xyz + (size_t)b * NP * 3;
    float px[32], py[32], pz[32], dist[32];
#pragma unroll
    for (int j = 0; j < 32; ++j) {
        const int p = tid + (j << 8);
        px[j] = xb[p * 3 + 0];
        py[j] = xb[p * 3 + 1];
        pz[j] = xb[p * 3 + 2];
        dist[j] = 1e10f;
    }
    __shared__ unsigned long long s_key[2][4];
    float cx = xb[0], cy = xb[1], cz = xb[2];
    float* ob = newxyz + (size_t)b * NS * 3;
    for (int it = 0; it < NS; ++it) {
        if (tid == 0) { ob[it * 3 + 0] = cx; ob[it * 3 + 1] = cy; ob[it * 3 + 2] = cz; }
        float bd = -1.0f; int bi = 0;
#pragma unroll
        for (int j = 0; j < 32; ++j) {
            float dx = px[j] - cx, dy = py[j] - cy, dz = pz[j] - cz;
            float d = (dx * dx + dy * dy) + dz * dz;   // match numpy order, no fma
            float dj = fminf(dist[j], d);
            dist[j] = dj;
            bool t = dj > bd;                           // strict > : first-occurrence tie-break
            bd = t ? dj : bd;
            bi = t ? (tid + (j << 8)) : bi;
        }
        // dist >= 0 always (sum of squares beats init -1 on j==0), so float bits
        // of bd are order-preserving as unsigned. Low word (NP-1-bi): on equal
        // dist, larger low word == smaller index -> numpy argmax tie-break.
        unsigned long long key = ((unsigned long long)__float_as_uint(bd) << 32)
                               | (unsigned)(NP - 1 - bi);
#pragma unroll
        for (int m = 1; m < 64; m <<= 1) {
            unsigned long long ok = __shfl_xor(key, m);
            key = (ok > key) ? ok : key;
        }
        if (lane == 0) s_key[it & 1][w] = key;
        __syncthreads();
        unsigned long long k0 = s_key[it & 1][0];
        unsigned long long k1 = s_key[it & 1][1];
        unsigned long long k2 = s_key[it & 1][2];
        unsigned long long k3 = s_key[it & 1][3];
        k0 = (k1 > k0) ? k1 : k0;
        k2 = (k3 > k2) ? k3 : k2;
        k0 = (k2 > k0) ? k2 : k0;
        const int fi = NP - 1 - (int)(unsigned)(k0 & 0xFFFFFFFFull);
        const float* cp = xb + (size_t)fi * 3;   // uniform broadcast load, L1/L2-hot
        cx = cp[0]; cy = cp[1]; cz = cp[2];
    }
}

// ---------------------------------------------------------------- ball query
// one wave per centroid; collect first NK point-indices (ascending) with d^2 <= r^2
__global__ __launch_bounds__(256) void ballq_kernel(const float* __restrict__ xyz,
                                                    const float* __restrict__ newxyz,
                                                    int* __restrict__ idxb)
{
#pragma clang fp contract(off)
    __shared__ int s_ball[4][NK];
    const int w = threadIdx.x >> 6;
    const int lane = threadIdx.x & 63;
    const int sg = blockIdx.x * 4 + w;          // 0..4095
    const int b = sg >> 10;
    const float rr = (float)(0.2 * 0.2);        // == f32(0.04000000000000001)
    const float cx = newxyz[sg * 3 + 0];
    const float cy = newxyz[sg * 3 + 1];
    const float cz = newxyz[sg * 3 + 2];
    const float* xb = xyz + (size_t)b * NP * 3;
    int cnt = 0;
    for (int base = 0; base < NP && cnt < NK; base += 64) {
        const int p = base + lane;
        float dx = xb[p * 3 + 0] - cx;
        float dy = xb[p * 3 + 1] - cy;
        float dz = xb[p * 3 + 2] - cz;
        float d = (dx * dx + dy * dy) + dz * dz;
        bool in = (d <= rr);
        unsigned long long mask = __ballot(in);
        int before = __popcll(mask & ((1ull << lane) - 1ull));
        int pos = cnt + before;
        if (in && pos < NK) s_ball[w][pos] = p;
        cnt += (int)__popcll(mask);
    }
    cnt = min(cnt, NK);
    if (lane < NK) {
        int v = (lane < cnt) ? s_ball[w][lane] : s_ball[w][0];
        idxb[(size_t)sg * NK + lane] = v;
    }
}

// ---------------------------------------------------------------- layer 1 (19 -> 64), pre-BN output
__global__ __launch_bounds__(256) void linear1_kernel(const float* __restrict__ xyz,
                                                      const float* __restrict__ pts,
                                                      const float* __restrict__ newxyz,
                                                      const int* __restrict__ idxb,
                                                      const float* __restrict__ w1,
                                                      const float* __restrict__ b1,
                                                      float* __restrict__ y1)
{
    const int P = blockIdx.x * 256 + threadIdx.x;    // 0..131071
    const int b = P >> 15;
    const int s = (P >> 5) & (NS - 1);
    const int id = idxb[P];
    const float* pp = xyz + ((size_t)b * NP + id) * 3;
    const float* cp = newxyz + ((size_t)b * NS + s) * 3;
    float f[19];
    f[0] = pp[0] - cp[0];
    f[1] = pp[1] - cp[1];
    f[2] = pp[2] - cp[2];
    const float* q = pts + ((size_t)b * NP + id) * 16;
#pragma unroll
    for (int j = 0; j < 16; ++j) f[3 + j] = q[j];
    float y[64];
#pragma unroll 4
    for (int c = 0; c < 64; ++c) {
        float a = b1[c];
#pragma unroll
        for (int j = 0; j < 19; ++j) a += w1[c * 19 + j] * f[j];
        y[c] = a;
    }
    float4* o = (float4*)(y1 + (size_t)P * 64);
#pragma unroll
    for (int t = 0; t < 16; ++t) o[t] = make_float4(y[4*t], y[4*t+1], y[4*t+2], y[4*t+3]);
}

// ---------------------------------------------------------------- per-channel sum/sumsq reduction
template <int C>
__global__ __launch_bounds__(256) void stats_kernel(const float* __restrict__ y,
                                                    float* __restrict__ sums,
                                                    float* __restrict__ sqs)
{
    const int RPB = 256 / C;
    const int c = threadIdx.x & (C - 1);
    const int rq = threadIdx.x / C;
    float s = 0.f, q = 0.f;
    for (int r = blockIdx.x * RPB + rq; r < 131072; r += gridDim.x * RPB) {
        float v = y[(size_t)r * C + c];
        s += v; q += v * v;
    }
    __shared__ float ls[256], lq[256];
    ls[threadIdx.x] = s; lq[threadIdx.x] = q;
    __syncthreads();
    if (threadIdx.x < C) {
        for (int i = 1; i < RPB; ++i) { s += ls[i * C + threadIdx.x]; q += lq[i * C + threadIdx.x]; }
        atomicAdd(&sums[(blockIdx.x & 7) * C + threadIdx.x], s);
        atomicAdd(&sqs [(blockIdx.x & 7) * C + threadIdx.x], q);
    }
}

template <int C>
__global__ void finalize_kernel(const float* __restrict__ sums, const float* __restrict__ sqs,
                                const float* __restrict__ g, const float* __restrict__ be,
                                float* __restrict__ scale, float* __restrict__ shift)
{
    const int c = threadIdx.x;
    if (c >= C) return;
    float s = 0.f, q = 0.f;
    for (int sh = 0; sh < 8; ++sh) { s += sums[sh * C + c]; q += sqs[sh * C + c]; }
    float mean = s / CNT_ALL;
    float var = q / CNT_ALL - mean * mean;
    float sc = g[c] / sqrtf(var + 1e-5f);
    scale[c] = sc;
    shift[c] = be[c] - mean * sc;
}

// ---------------------------------------------------------------- layer 2 (64 -> 64), pre-BN output
__global__ __launch_bounds__(256) void linear2_kernel(const float* __restrict__ y1,
                                                      const float* __restrict__ sc1,
                                                      const float* __restrict__ sh1,
                                                      const float* __restrict__ w2,
                                                      const float* __restrict__ b2,
                                                      float* __restrict__ y2)
{
    const int P = blockIdx.x * 256 + threadIdx.x;
    const float4* yi = (const float4*)(y1 + (size_t)P * 64);
    float x[64];
#pragma unroll
    for (int t = 0; t < 16; ++t) {
        float4 v = yi[t];
        x[4*t+0] = fmaxf(v.x * sc1[4*t+0] + sh1[4*t+0], 0.f);
        x[4*t+1] = fmaxf(v.y * sc1[4*t+1] + sh1[4*t+1], 0.f);
        x[4*t+2] = fmaxf(v.z * sc1[4*t+2] + sh1[4*t+2], 0.f);
        x[4*t+3] = fmaxf(v.w * sc1[4*t+3] + sh1[4*t+3], 0.f);
    }
    float y[64];
#pragma unroll 4
    for (int c = 0; c < 64; ++c) {
        float a = b2[c];
#pragma unroll
        for (int j = 0; j < 64; ++j) a += w2[c * 64 + j] * x[j];
        y[c] = a;
    }
    float4* o = (float4*)(y2 + (size_t)P * 64);
#pragma unroll
    for (int t = 0; t < 16; ++t) o[t] = make_float4(y[4*t], y[4*t+1], y[4*t+2], y[4*t+3]);
}

// ---------------------------------------------------------------- bn2+relu elementwise -> x2
__global__ __launch_bounds__(256) void bnrelu_kernel(const float* __restrict__ y2,
                                                     const float* __restrict__ sc,
                                                     const float* __restrict__ sh,
                                                     float* __restrict__ x2)
{
    const int i = blockIdx.x * 256 + threadIdx.x;    // float4 index, 2097152 total
    float4 v = ((const float4*)y2)[i];
    const int c = (i * 4) & 63;
    float4 o;
    o.x = fmaxf(v.x * sc[c + 0] + sh[c + 0], 0.f);
    o.y = fmaxf(v.y * sc[c + 1] + sh[c + 1], 0.f);
    o.z = fmaxf(v.z * sc[c + 2] + sh[c + 2], 0.f);
    o.w = fmaxf(v.w * sc[c + 3] + sh[c + 3], 0.f);
    ((float4*)x2)[i] = o;
}

// ---------------------------------------------------------------- layer 3 stats (no y3 store)
__global__ __launch_bounds__(128) void l3stats_kernel(const float* __restrict__ x2,
                                                      const float* __restrict__ w3,
                                                      const float* __restrict__ b3,
                                                      float* __restrict__ sums,
                                                      float* __restrict__ sqs)
{
    const int g = blockIdx.x;       // 4096 groups (b*NS+s)
    const int c = threadIdx.x;      // 128 channels
    float w[64];
    const float4* wr = (const float4*)(w3 + (size_t)c * 64);
#pragma unroll
    for (int t = 0; t < 16; ++t) {
        float4 v = wr[t];
        w[4*t+0] = v.x; w[4*t+1] = v.y; w[4*t+2] = v.z; w[4*t+3] = v.w;
    }
    const float bs = b3[c];
    float s = 0.f, q = 0.f;
    const float* xg = x2 + (size_t)g * NK * 64;
#pragma unroll 2
    for (int k = 0; k < NK; ++k) {
        const float4* xk = (const float4*)(xg + k * 64);
        float a = bs;
#pragma unroll
        for (int t = 0; t < 16; ++t) {
            float4 v = xk[t];
            a += w[4*t+0] * v.x + w[4*t+1] * v.y + w[4*t+2] * v.z + w[4*t+3] * v.w;
        }
        s += a; q += a * a;
    }
    atomicAdd(&sums[(g & 7) * 128 + c], s);
    atomicAdd(&sqs [(g & 7) * 128 + c], q);
}

// ---------------------------------------------------------------- layer 3 recompute + bn3 + relu + maxpool
__global__ __launch_bounds__(128) void final_kernel(const float* __restrict__ x2,
                                                    const float* __restrict__ w3,
                                                    const float* __restrict__ b3,
                                                    const float* __restrict__ sc3,
                                                    const float* __restrict__ sh3,
                                                    float* __restrict__ out_np)
{
    const int g = blockIdx.x;
    const int c = threadIdx.x;
    float w[64];
    const float4* wr = (const float4*)(w3 + (size_t)c * 64);
#pragma unroll
    for (int t = 0; t < 16; ++t) {
        float4 v = wr[t];
        w[4*t+0] = v.x; w[4*t+1] = v.y; w[4*t+2] = v.z; w[4*t+3] = v.w;
    }
    const float bs = b3[c];
    const float sc = sc3[c], sh = sh3[c];
    float m = -1e30f;
    const float* xg = x2 + (size_t)g * NK * 64;
#pragma unroll 2
    for (int k = 0; k < NK; ++k) {
        const float4* xk = (const float4*)(xg + k * 64);
        float a = bs;
#pragma unroll
        for (int t = 0; t < 16; ++t) {
            float4 v = xk[t];
            a += w[4*t+0] * v.x + w[4*t+1] * v.y + w[4*t+2] * v.z + w[4*t+3] * v.w;
        }
        float r = fmaxf(a * sc + sh, 0.f);
        m = fmaxf(m, r);
    }
    out_np[(size_t)g * 128 + c] = m;
}

// ---------------------------------------------------------------- host launch
extern "C" void kernel_launch(void* const* d_in, const int* in_sizes, int n_in,
                              void* d_out, int out_size, void* d_ws, size_t ws_size,
                              hipStream_t stream)
{
    (void)in_sizes; (void)n_in; (void)out_size;
    const float* xyz = (const float*)d_in[0];
    const float* pts = (const float*)d_in[1];
    const float* w1 = (const float*)d_in[2];
    const float* b1 = (const float*)d_in[3];
    const float* g1 = (const float*)d_in[4];
    const float* be1 = (const float*)d_in[5];
    const float* w2 = (const float*)d_in[6];
    const float* b2 = (const float*)d_in[7];
    const float* g2 = (const float*)d_in[8];
    const float* be2 = (const float*)d_in[9];
    const float* w3 = (const float*)d_in[10];
    const float* b3 = (const float*)d_in[11];
    const float* g3 = (const float*)d_in[12];
    const float* be3 = (const float*)d_in[13];

    float* out = (float*)d_out;
    float* newxyz = out;              // 4*1024*3
    float* newpts = out + NB * NS * 3;

    char* w = (char*)d_ws;
    int* idxb = (int*)w;                               // 131072 ints = 512 KB
    float* y1 = (float*)(w + (512 << 10));             // 8388608 f32
    float* y2 = y1 + 8388608;
    float* x2 = y2 + 8388608;
    float* st = x2 + 8388608;                          // stats: 3 layers * 2304 f32
    const size_t needed = (512ull << 10) + 3ull * 8388608ull * 4ull + 3ull * 2304ull * 4ull;
    if (ws_size < needed) return;                       // ws too small: bail cleanly

    float* sums1 = st,          *sqs1 = st + 1024,  *sc1 = st + 2048, *sh1 = st + 2176;
    float* st2 = st + 2304;
    float* sums2 = st2,         *sqs2 = st2 + 1024, *sc2 = st2 + 2048, *sh2 = st2 + 2176;
    float* st3 = st + 4608;
    float* sums3 = st3,         *sqs3 = st3 + 1024, *sc3 = st3 + 2048, *sh3 = st3 + 2176;

    hipMemsetAsync(st, 0, 3ull * 2304ull * 4ull, stream);

    fps_kernel<<<NB, 256, 0, stream>>>(xyz, newxyz);
    ballq_kernel<<<1024, 256, 0, stream>>>(xyz, newxyz, idxb);
    linear1_kernel<<<512, 256, 0, stream>>>(xyz, pts, newxyz, idxb, w1, b1, y1);
    stats_kernel<64><<<512, 256, 0, stream>>>(y1, sums1, sqs1);
    finalize_kernel<64><<<1, 64, 0, stream>>>(sums1, sqs1, g1, be1, sc1, sh1);
    linear2_kernel<<<512, 256, 0, stream>>>(y1, sc1, sh1, w2, b2, y2);
    stats_kernel<64><<<512, 256, 0, stream>>>(y2, sums2, sqs2);
    finalize_kernel<64><<<1, 64, 0, stream>>>(sums2, sqs2, g2, be2, sc2, sh2);
    bnrelu_kernel<<<8192, 256, 0, stream>>>(y2, sc2, sh2, x2);
    l3stats_kernel<<<4096, 128, 0, stream>>>(x2, w3, b3, sums3, sqs3);
    finalize_kernel<128><<<1, 128, 0, stream>>>(sums3, sqs3, g3, be3, sc3, sh3);
    final_kernel<<<4096, 128, 0, stream>>>(x2, w3, b3, sc3, sh3, newpts);
}

// Round 3
// 1291.169 us; speedup vs baseline: 1.4785x; 1.2594x over previous
//
#include <hip/hip_runtime.h>

#define NB 4
#define NP 8192
#define NS 1024
#define NK 32
#define CNT_ALL 131072.0f   // NB*NS*NK

typedef float v2f __attribute__((ext_vector_type(2)));

template <int CTRL>
__device__ __forceinline__ unsigned dpp_max_u32(unsigned m)
{
    unsigned o = (unsigned)__builtin_amdgcn_update_dpp((int)m, (int)m, CTRL, 0xF, 0xF, false);
    return (o > m) ? o : m;
}

template <int CTRL>
__device__ __forceinline__ unsigned long long dpp_max_u64(unsigned long long k)
{
    unsigned lo = (unsigned)k, hi = (unsigned)(k >> 32);
    unsigned olo = (unsigned)__builtin_amdgcn_update_dpp((int)lo, (int)lo, CTRL, 0xF, 0xF, false);
    unsigned ohi = (unsigned)__builtin_amdgcn_update_dpp((int)hi, (int)hi, CTRL, 0xF, 0xF, false);
    unsigned long long o = ((unsigned long long)ohi << 32) | (unsigned long long)olo;
    return (o > k) ? o : k;
}

// ---------------------------------------------------------------- FPS
// One block (512 thr, 8 waves) per batch. 16 pts/thread BLOCKED (thread t owns
// 16t..16t+15) so lowest-lane == lowest-index for numpy first-max tie-break.
// Distance state in float2 regs (v_pk_* candidates). Wave argmax: DPP max on
// float bits (dist>=0) + ballot/ffs/readlane for the index. Cross-wave: u64
// (dist_bits, 8191-idx) keys in LDS, broadcast-read + 3-step DPP u64 max.
// xyz staged in LDS SoA so the per-iter centroid broadcast never leaves the CU.
__global__ __launch_bounds__(512, 2) void fps_kernel(const float* __restrict__ xyz,
                                                     float* __restrict__ newxyz)
{
#pragma clang fp contract(off)
    const int b = blockIdx.x;
    const int tid = threadIdx.x;
    const int lane = tid & 63;
    const int w = tid >> 6;                 // 8 waves
    const float* xb = xyz + (size_t)b * NP * 3;

    __shared__ float s_px[NP], s_py[NP], s_pz[NP];      // 96 KB
    __shared__ unsigned long long s_key[2][8];

    v2f px[8], py[8], pz[8], dist[8];
    const int base = tid << 4;
#pragma unroll
    for (int m = 0; m < 8; ++m) {
        const int p0 = base + 2 * m;
        float x0 = xb[3 * p0 + 0], y0 = xb[3 * p0 + 1], z0 = xb[3 * p0 + 2];
        float x1 = xb[3 * p0 + 3], y1 = xb[3 * p0 + 4], z1 = xb[3 * p0 + 5];
        px[m] = v2f{x0, x1}; py[m] = v2f{y0, y1}; pz[m] = v2f{z0, z1};
        dist[m] = v2f{1e10f, 1e10f};
        s_px[p0] = x0; s_px[p0 + 1] = x1;
        s_py[p0] = y0; s_py[p0 + 1] = y1;
        s_pz[p0] = z0; s_pz[p0 + 1] = z1;
    }
    __syncthreads();
    float cx = s_px[0], cy = s_py[0], cz = s_pz[0];
    float* ob = newxyz + (size_t)b * NS * 3;

    for (int it = 0; it < NS; ++it) {
        if (tid == 0) { ob[it * 3 + 0] = cx; ob[it * 3 + 1] = cy; ob[it * 3 + 2] = cz; }
        const v2f cxx = v2f{cx, cx}, cyy = v2f{cy, cy}, czz = v2f{cz, cz};
        float bd0 = -1.0f, bd1 = -1.0f;
        int bj0 = 0, bj1 = 0;
#pragma unroll
        for (int m = 0; m < 8; ++m) {
            v2f dx = px[m] - cxx, dy = py[m] - cyy, dz = pz[m] - czz;
            v2f d = (dx * dx + dy * dy) + dz * dz;      // numpy order, no fma
            v2f dj = __builtin_elementwise_min(dist[m], d);
            dist[m] = dj;
            bool t0 = dj.x > bd0;                        // strict >: first max wins
            bd0 = t0 ? dj.x : bd0;
            bj0 = t0 ? 2 * m : bj0;
            bool t1 = dj.y > bd1;
            bd1 = t1 ? dj.y : bd1;
            bj1 = t1 ? 2 * m + 1 : bj1;
        }
        // merge even/odd chains; tie -> smaller local index
        const bool tm = (bd1 > bd0) || ((bd1 == bd0) && (bj1 < bj0));
        const float bd = tm ? bd1 : bd0;
        const int ibest = base + (tm ? bj1 : bj0);
        // wave max of dist bits (bd >= 0 so float bits are order-preserving)
        const unsigned ub = __float_as_uint(bd);
        unsigned m0 = dpp_max_u32<0xB1>(ub);    // quad_perm(1,0,3,2)  xor1
        m0 = dpp_max_u32<0x4E>(m0);             // quad_perm(2,3,0,1)  xor2
        m0 = dpp_max_u32<0x141>(m0);            // row_half_mirror     xor7
        m0 = dpp_max_u32<0x140>(m0);            // row_mirror          xor15
        m0 = dpp_max_u32<0x142>(m0);            // row_bcast15
        m0 = dpp_max_u32<0x143>(m0);            // row_bcast31 -> lane63 = wave max
        const unsigned maxbits = (unsigned)__builtin_amdgcn_readlane((int)m0, 63);
        const unsigned long long bm = __ballot(ub == maxbits);
        const int srclane = __ffsll((unsigned long long)bm) - 1;   // lowest lane = lowest idx
        const int wbi = __builtin_amdgcn_readlane(ibest, srclane);
        if (lane == 0) {
            const unsigned long long key =
                ((unsigned long long)maxbits << 32) | (unsigned)(NP - 1 - wbi);
            s_key[it & 1][w] = key;
        }
        __syncthreads();
        unsigned long long kk = s_key[it & 1][lane & 7];
        kk = dpp_max_u64<0xB1>(kk);
        kk = dpp_max_u64<0x4E>(kk);
        kk = dpp_max_u64<0x141>(kk);            // all 8 keys combined in every lane
        const int fi = NP - 1 - (int)(unsigned)(kk & 0xFFFFFFFFull);
        cx = s_px[fi]; cy = s_py[fi]; cz = s_pz[fi];   // LDS broadcast, ~120 cyc
    }
}

// ---------------------------------------------------------------- ball query
// one wave per centroid; collect first NK point-indices (ascending) with d^2 <= r^2
__global__ __launch_bounds__(256) void ballq_kernel(const float* __restrict__ xyz,
                                                    const float* __restrict__ newxyz,
                                                    int* __restrict__ idxb)
{
#pragma clang fp contract(off)
    __shared__ int s_ball[4][NK];
    const int w = threadIdx.x >> 6;
    const int lane = threadIdx.x & 63;
    const int sg = blockIdx.x * 4 + w;          // 0..4095
    const int b = sg >> 10;
    const float rr = (float)(0.2 * 0.2);        // == f32(0.04000000000000001)
    const float cx = newxyz[sg * 3 + 0];
    const float cy = newxyz[sg * 3 + 1];
    const float cz = newxyz[sg * 3 + 2];
    const float* xb = xyz + (size_t)b * NP * 3;
    int cnt = 0;
    for (int base = 0; base < NP && cnt < NK; base += 64) {
        const int p = base + lane;
        float dx = xb[p * 3 + 0] - cx;
        float dy = xb[p * 3 + 1] - cy;
        float dz = xb[p * 3 + 2] - cz;
        float d = (dx * dx + dy * dy) + dz * dz;
        bool in = (d <= rr);
        unsigned long long mask = __ballot(in);
        int before = __popcll(mask & ((1ull << lane) - 1ull));
        int pos = cnt + before;
        if (in && pos < NK) s_ball[w][pos] = p;
        cnt += (int)__popcll(mask);
    }
    cnt = min(cnt, NK);
    if (lane < NK) {
        int v = (lane < cnt) ? s_ball[w][lane] : s_ball[w][0];
        idxb[(size_t)sg * NK + lane] = v;
    }
}

// ---------------------------------------------------------------- layer 1 (19 -> 64), pre-BN output
__global__ __launch_bounds__(256) void linear1_kernel(const float* __restrict__ xyz,
                                                      const float* __restrict__ pts,
                                                      const float* __restrict__ newxyz,
                                                      const int* __restrict__ idxb,
                                                      const float* __restrict__ w1,
                                                      const float* __restrict__ b1,
                                                      float* __restrict__ y1)
{
    const int P = blockIdx.x * 256 + threadIdx.x;    // 0..131071
    const int b = P >> 15;
    const int s = (P >> 5) & (NS - 1);
    const int id = idxb[P];
    const float* pp = xyz + ((size_t)b * NP + id) * 3;
    const float* cp = newxyz + ((size_t)b * NS + s) * 3;
    float f[19];
    f[0] = pp[0] - cp[0];
    f[1] = pp[1] - cp[1];
    f[2] = pp[2] - cp[2];
    const float* q = pts + ((size_t)b * NP + id) * 16;
#pragma unroll
    for (int j = 0; j < 16; ++j) f[3 + j] = q[j];
    float y[64];
#pragma unroll 4
    for (int c = 0; c < 64; ++c) {
        float a = b1[c];
#pragma unroll
        for (int j = 0; j < 19; ++j) a += w1[c * 19 + j] * f[j];
        y[c] = a;
    }
    float4* o = (float4*)(y1 + (size_t)P * 64);
#pragma unroll
    for (int t = 0; t < 16; ++t) o[t] = make_float4(y[4*t], y[4*t+1], y[4*t+2], y[4*t+3]);
}

// ---------------------------------------------------------------- per-channel sum/sumsq reduction
template <int C>
__global__ __launch_bounds__(256) void stats_kernel(const float* __restrict__ y,
                                                    float* __restrict__ sums,
                                                    float* __restrict__ sqs)
{
    const int RPB = 256 / C;
    const int c = threadIdx.x & (C - 1);
    const int rq = threadIdx.x / C;
    float s = 0.f, q = 0.f;
    for (int r = blockIdx.x * RPB + rq; r < 131072; r += gridDim.x * RPB) {
        float v = y[(size_t)r * C + c];
        s += v; q += v * v;
    }
    __shared__ float ls[256], lq[256];
    ls[threadIdx.x] = s; lq[threadIdx.x] = q;
    __syncthreads();
    if (threadIdx.x < C) {
        for (int i = 1; i < RPB; ++i) { s += ls[i * C + threadIdx.x]; q += lq[i * C + threadIdx.x]; }
        atomicAdd(&sums[(blockIdx.x & 7) * C + threadIdx.x], s);
        atomicAdd(&sqs [(blockIdx.x & 7) * C + threadIdx.x], q);
    }
}

template <int C>
__global__ void finalize_kernel(const float* __restrict__ sums, const float* __restrict__ sqs,
                                const float* __restrict__ g, const float* __restrict__ be,
                                float* __restrict__ scale, float* __restrict__ shift)
{
    const int c = threadIdx.x;
    if (c >= C) return;
    float s = 0.f, q = 0.f;
    for (int sh = 0; sh < 8; ++sh) { s += sums[sh * C + c]; q += sqs[sh * C + c]; }
    float mean = s / CNT_ALL;
    float var = q / CNT_ALL - mean * mean;
    float sc = g[c] / sqrtf(var + 1e-5f);
    scale[c] = sc;
    shift[c] = be[c] - mean * sc;
}

// ---------------------------------------------------------------- layer 2 (64 -> 64), pre-BN output
__global__ __launch_bounds__(256) void linear2_kernel(const float* __restrict__ y1,
                                                      const float* __restrict__ sc1,
                                                      const float* __restrict__ sh1,
                                                      const float* __restrict__ w2,
                                                      const float* __restrict__ b2,
                                                      float* __restrict__ y2)
{
    const int P = blockIdx.x * 256 + threadIdx.x;
    const float4* yi = (const float4*)(y1 + (size_t)P * 64);
    float x[64];
#pragma unroll
    for (int t = 0; t < 16; ++t) {
        float4 v = yi[t];
        x[4*t+0] = fmaxf(v.x * sc1[4*t+0] + sh1[4*t+0], 0.f);
        x[4*t+1] = fmaxf(v.y * sc1[4*t+1] + sh1[4*t+1], 0.f);
        x[4*t+2] = fmaxf(v.z * sc1[4*t+2] + sh1[4*t+2], 0.f);
        x[4*t+3] = fmaxf(v.w * sc1[4*t+3] + sh1[4*t+3], 0.f);
    }
    float y[64];
#pragma unroll 4
    for (int c = 0; c < 64; ++c) {
        float a = b2[c];
#pragma unroll
        for (int j = 0; j < 64; ++j) a += w2[c * 64 + j] * x[j];
        y[c] = a;
    }
    float4* o = (float4*)(y2 + (size_t)P * 64);
#pragma unroll
    for (int t = 0; t < 16; ++t) o[t] = make_float4(y[4*t], y[4*t+1], y[4*t+2], y[4*t+3]);
}

// ---------------------------------------------------------------- bn2+relu elementwise -> x2
__global__ __launch_bounds__(256) void bnrelu_kernel(const float* __restrict__ y2,
                                                     const float* __restrict__ sc,
                                                     const float* __restrict__ sh,
                                                     float* __restrict__ x2)
{
    const int i = blockIdx.x * 256 + threadIdx.x;    // float4 index, 2097152 total
    float4 v = ((const float4*)y2)[i];
    const int c = (i * 4) & 63;
    float4 o;
    o.x = fmaxf(v.x * sc[c + 0] + sh[c + 0], 0.f);
    o.y = fmaxf(v.y * sc[c + 1] + sh[c + 1], 0.f);
    o.z = fmaxf(v.z * sc[c + 2] + sh[c + 2], 0.f);
    o.w = fmaxf(v.w * sc[c + 3] + sh[c + 3], 0.f);
    ((float4*)x2)[i] = o;
}

// ---------------------------------------------------------------- layer 3 stats (no y3 store)
__global__ __launch_bounds__(128) void l3stats_kernel(const float* __restrict__ x2,
                                                      const float* __restrict__ w3,
                                                      const float* __restrict__ b3,
                                                      float* __restrict__ sums,
                                                      float* __restrict__ sqs)
{
    const int g = blockIdx.x;       // 4096 groups (b*NS+s)
    const int c = threadIdx.x;      // 128 channels
    float w[64];
    const float4* wr = (const float4*)(w3 + (size_t)c * 64);
#pragma unroll
    for (int t = 0; t < 16; ++t) {
        float4 v = wr[t];
        w[4*t+0] = v.x; w[4*t+1] = v.y; w[4*t+2] = v.z; w[4*t+3] = v.w;
    }
    const float bs = b3[c];
    float s = 0.f, q = 0.f;
    const float* xg = x2 + (size_t)g * NK * 64;
#pragma unroll 2
    for (int k = 0; k < NK; ++k) {
        const float4* xk = (const float4*)(xg + k * 64);
        float a = bs;
#pragma unroll
        for (int t = 0; t < 16; ++t) {
            float4 v = xk[t];
            a += w[4*t+0] * v.x + w[4*t+1] * v.y + w[4*t+2] * v.z + w[4*t+3] * v.w;
        }
        s += a; q += a * a;
    }
    atomicAdd(&sums[(g & 7) * 128 + c], s);
    atomicAdd(&sqs [(g & 7) * 128 + c], q);
}

// ---------------------------------------------------------------- layer 3 recompute + bn3 + relu + maxpool
__global__ __launch_bounds__(128) void final_kernel(const float* __restrict__ x2,
                                                    const float* __restrict__ w3,
                                                    const float* __restrict__ b3,
                                                    const float* __restrict__ sc3,
                                                    const float* __restrict__ sh3,
                                                    float* __restrict__ out_np)
{
    const int g = blockIdx.x;
    const int c = threadIdx.x;
    float w[64];
    const float4* wr = (const float4*)(w3 + (size_t)c * 64);
#pragma unroll
    for (int t = 0; t < 16; ++t) {
        float4 v = wr[t];
        w[4*t+0] = v.x; w[4*t+1] = v.y; w[4*t+2] = v.z; w[4*t+3] = v.w;
    }
    const float bs = b3[c];
    const float sc = sc3[c], sh = sh3[c];
    float m = -1e30f;
    const float* xg = x2 + (size_t)g * NK * 64;
#pragma unroll 2
    for (int k = 0; k < NK; ++k) {
        const float4* xk = (const float4*)(xg + k * 64);
        float a = bs;
#pragma unroll
        for (int t = 0; t < 16; ++t) {
            float4 v = xk[t];
            a += w[4*t+0] * v.x + w[4*t+1] * v.y + w[4*t+2] * v.z + w[4*t+3] * v.w;
        }
        float r = fmaxf(a * sc + sh, 0.f);
        m = fmaxf(m, r);
    }
    out_np[(size_t)g * 128 + c] = m;
}

// ---------------------------------------------------------------- host launch
extern "C" void kernel_launch(void* const* d_in, const int* in_sizes, int n_in,
                              void* d_out, int out_size, void* d_ws, size_t ws_size,
                              hipStream_t stream)
{
    (void)in_sizes; (void)n_in; (void)out_size;
    const float* xyz = (const float*)d_in[0];
    const float* pts = (const float*)d_in[1];
    const float* w1 = (const float*)d_in[2];
    const float* b1 = (const float*)d_in[3];
    const float* g1 = (const float*)d_in[4];
    const float* be1 = (const float*)d_in[5];
    const float* w2 = (const float*)d_in[6];
    const float* b2 = (const float*)d_in[7];
    const float* g2 = (const float*)d_in[8];
    const float* be2 = (const float*)d_in[9];
    const float* w3 = (const float*)d_in[10];
    const float* b3 = (const float*)d_in[11];
    const float* g3 = (const float*)d_in[12];
    const float* be3 = (const float*)d_in[13];

    float* out = (float*)d_out;
    float* newxyz = out;              // 4*1024*3
    float* newpts = out + NB * NS * 3;

    char* w = (char*)d_ws;
    int* idxb = (int*)w;                               // 131072 ints = 512 KB
    float* y1 = (float*)(w + (512 << 10));             // 8388608 f32
    float* y2 = y1 + 8388608;
    float* x2 = y2 + 8388608;
    float* st = x2 + 8388608;                          // stats: 3 layers * 2304 f32
    const size_t needed = (512ull << 10) + 3ull * 8388608ull * 4ull + 3ull * 2304ull * 4ull;
    if (ws_size < needed) return;                       // ws too small: bail cleanly

    float* sums1 = st,          *sqs1 = st + 1024,  *sc1 = st + 2048, *sh1 = st + 2176;
    float* st2 = st + 2304;
    float* sums2 = st2,         *sqs2 = st2 + 1024, *sc2 = st2 + 2048, *sh2 = st2 + 2176;
    float* st3 = st + 4608;
    float* sums3 = st3,         *sqs3 = st3 + 1024, *sc3 = st3 + 2048, *sh3 = st3 + 2176;

    hipMemsetAsync(st, 0, 3ull * 2304ull * 4ull, stream);

    fps_kernel<<<NB, 512, 0, stream>>>(xyz, newxyz);
    ballq_kernel<<<1024, 256, 0, stream>>>(xyz, newxyz, idxb);
    linear1_kernel<<<512, 256, 0, stream>>>(xyz, pts, newxyz, idxb, w1, b1, y1);
    stats_kernel<64><<<512, 256, 0, stream>>>(y1, sums1, sqs1);
    finalize_kernel<64><<<1, 64, 0, stream>>>(sums1, sqs1, g1, be1, sc1, sh1);
    linear2_kernel<<<512, 256, 0, stream>>>(y1, sc1, sh1, w2, b2, y2);
    stats_kernel<64><<<512, 256, 0, stream>>>(y2, sums2, sqs2);
    finalize_kernel<64><<<1, 64, 0, stream>>>(sums2, sqs2, g2, be2, sc2, sh2);
    bnrelu_kernel<<<8192, 256, 0, stream>>>(y2, sc2, sh2, x2);
    l3stats_kernel<<<4096, 128, 0, stream>>>(x2, w3, b3, sums3, sqs3);
    finalize_kernel<128><<<1, 128, 0, stream>>>(sums3, sqs3, g3, be3, sc3, sh3);
    final_kernel<<<4096, 128, 0, stream>>>(x2, w3, b3, sc3, sh3, newpts);
}